// Round 14
// baseline (147.140 us; speedup 1.0000x reference)
//
#include <hip/hip_runtime.h>
#include <hip/hip_fp16.h>

#define NELEM 8388608    // 8*256*64*64
#define M_GAP 6e-4f      // >> 2*(eps_fp16 + rho_np) ~ 1.7e-4 (safe margin)
#define SCORE_SCALE (-1.0f / 512.0f)

typedef _Float16 f16x8 __attribute__((ext_vector_type(8)));
typedef short s16x8 __attribute__((ext_vector_type(8)));
typedef float f32x4 __attribute__((ext_vector_type(4)));

__device__ __forceinline__ unsigned short bf16r(float f) {
  unsigned u = __float_as_uint(f);
  return (unsigned short)((u + 0x7fffu + ((u >> 16) & 1u)) >> 16);
}
__device__ __forceinline__ float bf16f(unsigned short h) {
  return __uint_as_float(((unsigned)h) << 16);
}

// numpy pairwise sum of squares (n=256): two 128-blocks of 8 accumulators.
__device__ __forceinline__ float pw128_sq(const float* p, int s) {
  float r[8];
#pragma unroll
  for (int j = 0; j < 8; ++j) { float v = p[j * s]; r[j] = __fmul_rn(v, v); }
#pragma unroll
  for (int i = 8; i < 128; i += 8) {
#pragma unroll
    for (int j = 0; j < 8; ++j) {
      float v = p[(i + j) * s];
      r[j] = __fadd_rn(r[j], __fmul_rn(v, v));
    }
  }
  return __fadd_rn(__fadd_rn(__fadd_rn(r[0], r[1]), __fadd_rn(r[2], r[3])),
                   __fadd_rn(__fadd_rn(r[4], r[5]), __fadd_rn(r[6], r[7])));
}
__device__ __forceinline__ float np_sumsq256(const float* p, int s) {
  return __fadd_rn(pw128_sq(p, s), pw128_sq(p + 128 * s, s));
}

// ---- prep: fp16(x1024) codebook in wave-direct frag layout + cbT + norms ----
__global__ __launch_bounds__(256)
void vq_prep(const float* __restrict__ cb, unsigned short* __restrict__ cbimg,
             float* __restrict__ cbT, float* __restrict__ Bsg,
             unsigned* __restrict__ cnt, float* __restrict__ loss) {
  int gid = blockIdx.x * 256 + threadIdx.x;   // 0..4095
  if (gid == 0) { cnt[0] = 0u; cnt[1] = 0u; *loss = 0.0f; }
  int j = gid >> 2, qt = gid & 3;
  const float4* row4 = reinterpret_cast<const float4*>(cb + (size_t)j * 256 + qt * 64);
  int T = j >> 4, jj = j & 15;
#pragma unroll
  for (int m8 = 0; m8 < 8; ++m8) {
    int c0 = qt * 64 + m8 * 8;                // 8-aligned c block
    int kk = c0 >> 5, lk = (c0 >> 3) & 3;
    float4 va = row4[m8 * 2];
    float4 vb = row4[m8 * 2 + 1];
    float v[8] = {va.x, va.y, va.z, va.w, vb.x, vb.y, vb.z, vb.w};
    s16x8 hv;
#pragma unroll
    for (int q = 0; q < 8; ++q) {
      hv[q] = (short)__half_as_ushort(__float2half(v[q] * 1024.0f));
      cbT[(size_t)(c0 + q) * 1024 + j] = v[q];
    }
    *reinterpret_cast<s16x8*>(cbimg + (size_t)T * 4096 + kk * 512 + (lk * 16 + jj) * 8) = hv;
  }
  if (qt == 0) Bsg[j] = np_sumsq256(cb + (size_t)j * 256, 1);
}

// one 16-code tile: 8 kk MFMA x 4 row-subtiles + running TOP-3 update.
#define VQ_STEP_PF(IT2, DO_PF)                                                 \
  {                                                                            \
    f32x4 acc[4];                                                              \
    _Pragma("unroll")                                                          \
    for (int rs = 0; rs < 4; ++rs) acc[rs] = (f32x4){0.f, 0.f, 0.f, 0.f};      \
    _Pragma("unroll")                                                          \
    for (int kk = 0; kk < 8; ++kk) {                                           \
      f16x8 bcur = ba[kk];                                                     \
      if (DO_PF)                                                               \
        ba[kk] = cimg2[(size_t)(wv * 16 + (IT2) + 1) * 512 + kk * 64 + lane];  \
      _Pragma("unroll")                                                        \
      for (int rs = 0; rs < 4; ++rs)                                           \
        acc[rs] = __builtin_amdgcn_mfma_f32_16x16x32_f16(ah[rs][kk], bcur,     \
                                                         acc[rs], 0, 0, 0);    \
    }                                                                          \
    int j = wv * 256 + (IT2) * 16 + l15;                                       \
    float Bj = BsL[j];                                                         \
    _Pragma("unroll")                                                          \
    for (int rs = 0; rs < 4; ++rs) {                                           \
      _Pragma("unroll")                                                        \
      for (int r = 0; r < 4; ++r) {                                            \
        float s = fmaf(SCORE_SCALE, acc[rs][r], Bj);                           \
        bool lt1 = s < b1v[rs][r];                                             \
        bool lt2 = s < b2v[rs][r];                                             \
        bool lt3 = s < b3v[rs][r];                                             \
        b3v[rs][r] = lt2 ? b2v[rs][r] : (lt3 ? s : b3v[rs][r]);                \
        b2v[rs][r] = lt1 ? b1v[rs][r] : (lt2 ? s : b2v[rs][r]);                \
        b2i[rs][r] = lt1 ? b1i[rs][r] : (lt2 ? j : b2i[rs][r]);                \
        b1v[rs][r] = lt1 ? s : b1v[rs][r];                                     \
        b1i[rs][r] = lt1 ? j : b1i[rs][r];                                     \
      }                                                                        \
    }                                                                          \
  }

// ---- fast: 512 blocks x 64 rows, 4 waves code-partitioned, B global->reg ----
// (256,1) + padded LDS (73.5 KB -> exactly 2 blocks/CU) pins the allocator at
// a 256-VGPR budget so the 128-VGPR ah stays in registers (r13 verified: 168).
__global__ __launch_bounds__(256, 1)
void vq_fast(const float* __restrict__ z, const float* __restrict__ cb,
             const unsigned short* __restrict__ cbimg,
             const float* __restrict__ Bsg,
             float* __restrict__ zq, float* __restrict__ loss,
             float* __restrict__ idxo,
             unsigned* __restrict__ plist, unsigned* __restrict__ pcand,
             unsigned* __restrict__ flist, unsigned* __restrict__ cnt,
             float* __restrict__ zdump) {
  __shared__ __align__(16) unsigned char buf[58880]; // zt / epilogue ldsF; padded (occupancy pin)
  __shared__ float BsL[1024];
  __shared__ float part[32][36];
  __shared__ float rowA[64];
  __shared__ int bestj[64];
  __shared__ float bestd[64];
  __shared__ float wred[4];
  __shared__ float cv1[4 * 64], cv2[4 * 64], cv3[4 * 64];
  __shared__ int ci1[4 * 64], ci2[4 * 64];

  const int t = threadIdx.x;
  const int bid = blockIdx.x;          // = bh; rows n0 = bid*64
  const int lane = t & 63;
  const int wv = t >> 6;               // wave 0..3: codes wv*256..+255
  const int l15 = lane & 15;
  const int lk = lane >> 4;            // 0..3

  const f16x8* cimg2 = reinterpret_cast<const f16x8*>(cbimg);  // 16B units
  float* zt = reinterpret_cast<float*>(buf);   // [256 c][33] f32 during A-stage
  const float4* z4 = reinterpret_cast<const float4*>(
      z + (size_t)(bid >> 6) * 1048576 + (size_t)(bid & 63) * 64);

  // issue tile-0 loads of this wave's quarter early (latency under A-stage)
  f16x8 ba[8];
#pragma unroll
  for (int kk = 0; kk < 8; ++kk)
    ba[kk] = cimg2[(size_t)(wv * 16) * 512 + kk * 64 + lane];

  for (int i = t; i < 1024; i += 256) BsL[i] = Bsg[i];

  f16x8 ah[4][8];                      // all 64 rows: 4 subtiles x 8 k-steps
  // ---- A staging in halves of 32 rows (UNROLLED: ah indices static) ----
#pragma unroll
  for (int hp = 0; hp < 2; ++hp) {
    float sq[4] = {0.f, 0.f, 0.f, 0.f};
#pragma unroll
    for (int i = 0; i < 8; ++i) {
      int idx = t + i * 256;           // c = idx>>3, w4p = idx&7
      int c = idx >> 3, w4p = idx & 7;
      float4 v = z4[(size_t)c * 1024 + hp * 8 + w4p];
      zt[c * 33 + w4p * 4 + 0] = v.x;
      zt[c * 33 + w4p * 4 + 1] = v.y;
      zt[c * 33 + w4p * 4 + 2] = v.z;
      zt[c * 33 + w4p * 4 + 3] = v.w;
      sq[0] += v.x * v.x; sq[1] += v.y * v.y;
      sq[2] += v.z * v.z; sq[3] += v.w * v.w;
    }
#pragma unroll
    for (int q = 0; q < 4; ++q) part[t >> 3][(t & 7) * 4 + q] = sq[q];
    __syncthreads();
    if (t < 32) {
      float s = 0.f;
#pragma unroll
      for (int g = 0; g < 32; ++g) s += part[g][t];
      rowA[hp * 32 + t] = s;
    }
    // every wave loads a-frags for BOTH row-subtiles of this half (fp16 RNE)
#pragma unroll
    for (int rr2 = 0; rr2 < 2; ++rr2) {
      int lr = rr2 * 16 + l15;         // row within half
#pragma unroll
      for (int kk = 0; kk < 8; ++kk)
#pragma unroll
        for (int m = 0; m < 8; ++m)
          ah[hp * 2 + rr2][kk][m] = (_Float16)zt[(kk * 32 + lk * 8 + m) * 33 + lr];
    }
    // z-dump (coalesced [n][c]) for the pair/full rescore passes
#pragma unroll
    for (int i = 0; i < 8; ++i) {
      int item = t + i * 256;          // c4 = item&63, rowp = item>>6 in [0,32)
      int c4 = item & 63, rowp = item >> 6;
      float4 v = make_float4(zt[(c4 * 4 + 0) * 33 + rowp],
                             zt[(c4 * 4 + 1) * 33 + rowp],
                             zt[(c4 * 4 + 2) * 33 + rowp],
                             zt[(c4 * 4 + 3) * 33 + rowp]);
      *reinterpret_cast<float4*>(
          zdump + ((size_t)bid * 64 + hp * 32 + rowp) * 256 + c4 * 4) = v;
    }
    __syncthreads();
  }

  float b1v[4][4], b2v[4][4], b3v[4][4];
  int b1i[4][4], b2i[4][4];
#pragma unroll
  for (int rs = 0; rs < 4; ++rs)
#pragma unroll
    for (int r = 0; r < 4; ++r) {
      b1v[rs][r] = 3.4e38f; b2v[rs][r] = 3.4e38f; b3v[rs][r] = 3.4e38f;
      b1i[rs][r] = 0; b2i[rs][r] = 0;
    }

  // barrier-free main loop over this wave's 16 private tiles
  for (int it = 0; it < 15; ++it) {
    VQ_STEP_PF(it, true);
  }
  VQ_STEP_PF(15, false);

  // ---- merge top-3 across the 16 lanes sharing rows (within wave) ----
#pragma unroll
  for (int mk = 1; mk < 16; mk <<= 1) {
#pragma unroll
    for (int rs = 0; rs < 4; ++rs)
#pragma unroll
      for (int r = 0; r < 4; ++r) {
        float ov1 = __shfl_xor(b1v[rs][r], mk, 64);
        float ov2 = __shfl_xor(b2v[rs][r], mk, 64);
        float ov3 = __shfl_xor(b3v[rs][r], mk, 64);
        int oi1 = __shfl_xor(b1i[rs][r], mk, 64);
        int oi2 = __shfl_xor(b2i[rs][r], mk, 64);
        bool bw = ov1 < b1v[rs][r];      // other's seq wins first place
        float w2 = bw ? ov2 : b2v[rs][r];
        int wi2 = bw ? oi2 : b2i[rs][r];
        float w3 = bw ? ov3 : b3v[rs][r];
        float l1 = bw ? b1v[rs][r] : ov1;
        int li1 = bw ? b1i[rs][r] : oi1;
        float l2 = bw ? b2v[rs][r] : ov2;
        b1v[rs][r] = bw ? ov1 : b1v[rs][r];
        b1i[rs][r] = bw ? oi1 : b1i[rs][r];
        bool sw = w2 < l1;
        b2v[rs][r] = sw ? w2 : l1;
        b2i[rs][r] = sw ? wi2 : li1;
        b3v[rs][r] = sw ? fminf(w3, l1) : fminf(w2, l2);
      }
  }
  if (l15 == 0) {
#pragma unroll
    for (int rs = 0; rs < 4; ++rs)
#pragma unroll
      for (int r = 0; r < 4; ++r) {
        int rr = rs * 16 + lk * 4 + r;     // D row = (lane>>4)*4 + reg
        cv1[wv * 64 + rr] = b1v[rs][r];
        cv2[wv * 64 + rr] = b2v[rs][r];
        cv3[wv * 64 + rr] = b3v[rs][r];
        ci1[wv * 64 + rr] = b1i[rs][r];
        ci2[wv * 64 + rr] = b2i[rs][r];
      }
  }
  __syncthreads();

  // ---- cross-wave top-3 merge (wave order = ascending code ranges) ----
  if (t < 64) {
    float v1 = cv1[t], v2 = cv2[t], v3 = cv3[t];
    int i1 = ci1[t], i2 = ci2[t];
#pragma unroll
    for (int w = 1; w < 4; ++w) {
      float u1 = cv1[w * 64 + t], u2 = cv2[w * 64 + t], u3 = cv3[w * 64 + t];
      int ui1 = ci1[w * 64 + t], ui2 = ci2[w * 64 + t];
      bool bw = u1 < v1;
      float w2 = bw ? u2 : v2;  int wi2 = bw ? ui2 : i2;
      float w3 = bw ? u3 : v3;
      float l1 = bw ? v1 : u1;  int li1 = bw ? i1 : ui1;
      float l2 = bw ? v2 : u2;
      v1 = bw ? u1 : v1;  i1 = bw ? ui1 : i1;
      bool sw = w2 < l1;
      v2 = sw ? w2 : l1;  i2 = sw ? wi2 : li1;
      v3 = sw ? fminf(w3, l1) : fminf(w2, l2);
    }
    bestj[t] = i1;
    bestd[t] = v1;
    int n = bid * 64 + t;
    idxo[n] = (float)i1;               // provisional for flagged rows
    if (v2 - v1 <= M_GAP) {
      if (v3 - v1 > M_GAP) {           // np-winner provably in {i1,i2}
        unsigned pos = atomicAdd(&cnt[0], 1u);
        plist[pos] = (unsigned)n;
        pcand[pos] = (unsigned)i1 | ((unsigned)i2 << 16);
      } else {                          // 3+ candidates: full rescore
        unsigned pos = atomicAdd(&cnt[1], 1u);
        flist[pos] = (unsigned)n;
      }
    }
  }
  __syncthreads();

  // loss over ALL rows (flagged rows' provisional s_best within tolerance)
  {
    float lv = (t < 64) ? (rowA[t] + bestd[t]) : 0.f;
#pragma unroll
    for (int off = 32; off > 0; off >>= 1) lv += __shfl_down(lv, off, 64);
    if (lane == 0) wred[wv] = lv;
  }
  __syncthreads();
  if (t == 0)
    atomicAdd(loss, (wred[0] + wred[1] + wred[2] + wred[3]) * (1.25f / (float)NELEM));

  // ---- zq gather in halves: cb rows -> LDS transpose -> coalesced write ----
  f32x4* ldsF4 = reinterpret_cast<f32x4*>(buf);
  const float* ldsF = reinterpret_cast<const float*>(buf);
  const float4* cb4 = reinterpret_cast<const float4*>(cb);
  float* zqb = zq + (size_t)(bid >> 6) * 1048576 + (size_t)(bid & 63) * 64;
  for (int hp = 0; hp < 2; ++hp) {
    __syncthreads();
#pragma unroll
    for (int i = 0; i < 8; ++i) {
      int item = t + i * 256;            // rr = item>>6 in [0,32), cc = item&63
      int rr = item >> 6, cc = item & 63;
      float4 v = cb4[(size_t)bestj[hp * 32 + rr] * 64 + cc];
      ldsF4[rr * 64 + (cc ^ ((rr >> 2) & 7))] = (f32x4){v.x, v.y, v.z, v.w};
    }
    __syncthreads();
#pragma unroll
    for (int i = 0; i < 8; ++i) {
      int item = t + i * 256;            // w4p = item&7, c = item>>3
      int w4p = item & 7, c = item >> 3;
      float ov[4];
#pragma unroll
      for (int q = 0; q < 4; ++q) {
        int rr = w4p * 4 + q;
        ov[q] = ldsF[(rr * 64 + ((c >> 2) ^ ((rr >> 2) & 7))) * 4 + (c & 3)];
      }
      *reinterpret_cast<float4*>(zqb + (size_t)c * 4096 + hp * 32 + w4p * 4) =
          make_float4(ov[0], ov[1], ov[2], ov[3]);
    }
  }
}

// ---- pair rescore: np-exact d for {i1,i2} only, one thread per row ----
__global__ __launch_bounds__(256)
void vq_pair(const float* __restrict__ zdump, const float* __restrict__ cb,
             const float* __restrict__ Bsg, const unsigned* __restrict__ plist,
             const unsigned* __restrict__ pcand, const unsigned* __restrict__ cnt,
             float* __restrict__ idxo) {
  const unsigned K = cnt[0];
  for (unsigned idx = blockIdx.x * 256 + threadIdx.x; idx < K;
       idx += gridDim.x * 256) {
    int n = (int)plist[idx];
    unsigned pk = pcand[idx];
    int j1 = (int)(pk & 0xffffu), j2 = (int)(pk >> 16);
    const float* zr = zdump + (size_t)n * 256;
    const float* c1 = cb + (size_t)j1 * 256;
    const float* c2 = cb + (size_t)j2 * 256;
    float A = np_sumsq256(zr, 1);
    float C1 = 0.f, C2 = 0.f;
    for (int c = 0; c < 256; ++c) {
      float zc = zr[c];
      C1 = fmaf(zc, c1[c], C1);
      C2 = fmaf(zc, c2[c], C2);
    }
    float d1 = __fsub_rn(__fadd_rn(A, Bsg[j1]), __fmul_rn(2.0f, C1));
    float d2 = __fsub_rn(__fadd_rn(A, Bsg[j2]), __fmul_rn(2.0f, C2));
    int win = (d2 < d1 || (d2 == d1 && j2 < j1)) ? j2 : j1;
    idxo[n] = (float)win;
  }
}

// ---- full rescore (rare 3+-way ties): batched 8 rows, zdump, idx-only ----
__global__ __launch_bounds__(256)
void vq_exact_fast(const float* __restrict__ zdump, const float* __restrict__ cbT,
                   const float* __restrict__ Bsg, const unsigned* __restrict__ list,
                   const unsigned* __restrict__ cnt, float* __restrict__ idxo) {
  __shared__ float zr[8][260];
  __shared__ float Anp[8];
  __shared__ float rv[256];
  __shared__ int ri[256];
  const int t = threadIdx.x;
  const unsigned K = *cnt;
  const float4* cbT4 = reinterpret_cast<const float4*>(cbT);
  const float4* zd4 = reinterpret_cast<const float4*>(zdump);

  for (unsigned g = blockIdx.x; g * 8 < K; g += gridDim.x) {
    int nrows = (int)min(8u, K - g * 8);
    __syncthreads();
#pragma unroll
    for (int i = 0; i < 2; ++i) {
      int idx = t + i * 256;             // r = idx>>6, c4 = idx&63
      int r = idx >> 6, c4 = idx & 63;
      if (r < nrows) {
        float4 v = zd4[(size_t)list[g * 8 + r] * 64 + c4];
        zr[r][c4 * 4 + 0] = v.x; zr[r][c4 * 4 + 1] = v.y;
        zr[r][c4 * 4 + 2] = v.z; zr[r][c4 * 4 + 3] = v.w;
      }
    }
    __syncthreads();
    if (t < nrows) Anp[t] = np_sumsq256(&zr[t][0], 1);
    __syncthreads();

    float acc[8][4];
#pragma unroll
    for (int r = 0; r < 8; ++r)
#pragma unroll
      for (int q = 0; q < 4; ++q) acc[r][q] = 0.f;
    for (int c = 0; c < 256; ++c) {
      float4 bv = cbT4[c * 256 + t];
#pragma unroll
      for (int r = 0; r < 8; ++r) {
        float zc = zr[r][c];
        acc[r][0] = fmaf(zc, bv.x, acc[r][0]);
        acc[r][1] = fmaf(zc, bv.y, acc[r][1]);
        acc[r][2] = fmaf(zc, bv.z, acc[r][2]);
        acc[r][3] = fmaf(zc, bv.w, acc[r][3]);
      }
    }
    for (int r = 0; r < nrows; ++r) {
      float A = Anp[r];
      float bvv = 3.4e38f;
      int bii = 0;
#pragma unroll
      for (int q = 0; q < 4; ++q) {
        int j = t * 4 + q;
        float dd = __fsub_rn(__fadd_rn(A, Bsg[j]), __fmul_rn(2.0f, acc[r][q]));
        if (dd < bvv) { bvv = dd; bii = j; }
      }
      rv[t] = bvv; ri[t] = bii;
      __syncthreads();
      for (int s2 = 128; s2 > 0; s2 >>= 1) {
        if (t < s2) {
          float v2 = rv[t + s2]; int i2 = ri[t + s2];
          if (v2 < rv[t] || (v2 == rv[t] && i2 < ri[t])) { rv[t] = v2; ri[t] = i2; }
        }
        __syncthreads();
      }
      if (t == 0) idxo[list[g * 8 + r]] = (float)ri[0];
      __syncthreads();
    }
  }
}

// ---- fallback (round-2 validated all-exact kernel) ----
__global__ __launch_bounds__(256)
void vq_ref(const float* __restrict__ z, const float* __restrict__ cb,
            float* __restrict__ zq, float* __restrict__ loss,
            float* __restrict__ idxo) {
  __shared__ __align__(16) float zt[256 * 64];
  __shared__ __align__(16) float cbt[256 * 64];
  __shared__ float As[64];
  __shared__ float Bs[64];
  __shared__ int bestj[64];
  __shared__ float cand_v[16 * 64];
  __shared__ int cand_i[16 * 64];
  __shared__ double wred[4];
  const int t = threadIdx.x;
  const int wg = t & 15, jg = t >> 4;
  const int bid = blockIdx.x;
  const int b = bid >> 6, h = bid & 63;
  const int n0 = bid * 64;
  const float4* z4 = reinterpret_cast<const float4*>(z + (size_t)b * 256 * 4096 + (size_t)h * 64);
  float4* zt4 = reinterpret_cast<float4*>(zt);
#pragma unroll
  for (int i = 0; i < 16; ++i) {
    int idx4 = t + i * 256;
    zt4[idx4] = z4[(size_t)(idx4 >> 4) * 1024 + (idx4 & 15)];
  }
  __syncthreads();
  if (t < 64) As[t] = np_sumsq256(zt + t, 64);
  float bv[4]; int bi[4];
#pragma unroll
  for (int a = 0; a < 4; ++a) { bv[a] = 3.4e38f; bi[a] = 0; }
  for (int p = 0; p < 16; ++p) {
    __syncthreads();
    const float4* cb4 = reinterpret_cast<const float4*>(cb) + (size_t)p * 64 * 64;
#pragma unroll
    for (int i = 0; i < 16; ++i) {
      int idx4 = t + i * 256;
      int jj = idx4 >> 6, c4 = idx4 & 63;
      float4 v = cb4[idx4];
      cbt[(c4 * 4 + 0) * 64 + jj] = v.x;
      cbt[(c4 * 4 + 1) * 64 + jj] = v.y;
      cbt[(c4 * 4 + 2) * 64 + jj] = v.z;
      cbt[(c4 * 4 + 3) * 64 + jj] = v.w;
    }
    __syncthreads();
    if (t < 64) Bs[t] = np_sumsq256(cbt + t, 64);
    float acc[4][4];
#pragma unroll
    for (int a = 0; a < 4; ++a)
#pragma unroll
      for (int u = 0; u < 4; ++u) acc[a][u] = 0.0f;
    const float4* ztp = reinterpret_cast<const float4*>(zt) + wg;
    const float4* cbp = reinterpret_cast<const float4*>(cbt) + jg;
#pragma unroll 4
    for (int c = 0; c < 256; ++c) {
      float4 zv = ztp[c * 16];
      float4 cv = cbp[c * 16];
      float za[4] = {zv.x, zv.y, zv.z, zv.w};
      float ca[4] = {cv.x, cv.y, cv.z, cv.w};
#pragma unroll
      for (int a = 0; a < 4; ++a)
#pragma unroll
        for (int u = 0; u < 4; ++u) acc[a][u] = fmaf(za[a], ca[u], acc[a][u]);
    }
    __syncthreads();
#pragma unroll
    for (int u = 0; u < 4; ++u) {
      int j = p * 64 + jg * 4 + u;
      float Bju = Bs[jg * 4 + u];
#pragma unroll
      for (int a = 0; a < 4; ++a) {
        float AB = __fadd_rn(As[wg * 4 + a], Bju);
        float dd = __fsub_rn(AB, __fmul_rn(2.0f, acc[a][u]));
        if (dd < bv[a]) { bv[a] = dd; bi[a] = j; }
      }
    }
  }
  __syncthreads();
#pragma unroll
  for (int a = 0; a < 4; ++a) {
    int w = wg * 4 + a;
    cand_v[jg * 64 + w] = bv[a];
    cand_i[jg * 64 + w] = bi[a];
  }
  __syncthreads();
  if (t < 64) {
    float v0 = cand_v[t]; int i0 = cand_i[t];
    for (int g = 1; g < 16; ++g) {
      float v = cand_v[g * 64 + t]; int ii = cand_i[g * 64 + t];
      if (v < v0 || (v == v0 && ii < i0)) { v0 = v; i0 = ii; }
    }
    bestj[t] = i0;
    idxo[n0 + t] = (float)i0;
  }
  __syncthreads();
  double lsum = 0.0;
  float* zqbase = zq + (size_t)b * 256 * 4096 + (size_t)h * 64;
  for (int i = 0; i < 64; ++i) {
    int idx = t + i * 256;
    int c = idx >> 6, w = idx & 63;
    float zvv = zt[c * 64 + w];
    float cvv = cb[(size_t)bestj[w] * 256 + c];
    zqbase[(size_t)c * 4096 + w] = cvv;
    double d = (double)cvv - (double)zvv;
    lsum += d * d;
  }
#pragma unroll
  for (int off = 32; off > 0; off >>= 1) lsum += __shfl_down(lsum, off, 64);
  if ((t & 63) == 0) wred[t >> 6] = lsum;
  __syncthreads();
  if (t == 0) {
    double tot = wred[0] + wred[1] + wred[2] + wred[3];
    atomicAdd(loss, (float)(tot * (1.25 / (double)NELEM)));
  }
}

extern "C" void kernel_launch(void* const* d_in, const int* in_sizes, int n_in,
                              void* d_out, int out_size, void* d_ws, size_t ws_size,
                              hipStream_t stream) {
  (void)in_sizes; (void)n_in; (void)out_size;
  const float* z = (const float*)d_in[0];
  const float* cb = (const float*)d_in[1];
  float* out = (float*)d_out;
  float* zq = out;
  float* loss = out + NELEM;
  float* idxo = out + NELEM + 1;
  if (ws_size < 35651584) {  // need zdump: else validated all-exact path
    hipMemsetAsync(loss, 0, sizeof(float), stream);
    vq_ref<<<512, 256, 0, stream>>>(z, cb, zq, loss, idxo);
    return;
  }
  unsigned char* ws = (unsigned char*)d_ws;
  unsigned* cnt = (unsigned*)ws;                             // 2 x u32
  float* Bsg = (float*)(ws + 1024);                          // 4 KB
  unsigned* plist = (unsigned*)(ws + 8192);                  // 128 KB
  unsigned* pcand = (unsigned*)(ws + 139264);                // 128 KB
  unsigned* flist = (unsigned*)(ws + 270336);                // 128 KB
  float* cbT = (float*)(ws + 401408);                        // 1 MB
  unsigned short* cbimg = (unsigned short*)(ws + 1449984);   // 512 KB fp16 frag-layout
  float* zdump = (float*)(ws + 2097152);                     // 32 MB
  vq_prep<<<16, 256, 0, stream>>>(cb, cbimg, cbT, Bsg, cnt, loss);
  vq_fast<<<512, 256, 0, stream>>>(z, cb, cbimg, Bsg, zq, loss, idxo,
                                   plist, pcand, flist, cnt, zdump);
  vq_pair<<<64, 256, 0, stream>>>(zdump, cb, Bsg, plist, pcand, cnt, idxo);
  vq_exact_fast<<<64, 256, 0, stream>>>(zdump, cbT, Bsg, flist, cnt + 1, idxo);
}

// Round 15
// 100.676 us; speedup vs baseline: 1.4615x; 1.4615x over previous
//
#include <hip/hip_runtime.h>
#include <hip/hip_fp16.h>

#define NELEM 8388608    // 8*256*64*64
#define M_GAP 6e-4f      // validated rounds 6/8/9/13 (fp16 1-plane, x1024 codebook)
#define SCORE_SCALE (-1.0f / 512.0f)

typedef _Float16 f16x8 __attribute__((ext_vector_type(8)));
typedef short s16x8 __attribute__((ext_vector_type(8)));
typedef float f32x4 __attribute__((ext_vector_type(4)));

__device__ __forceinline__ unsigned short bf16r(float f) {
  unsigned u = __float_as_uint(f);
  return (unsigned short)((u + 0x7fffu + ((u >> 16) & 1u)) >> 16);
}
__device__ __forceinline__ float bf16f(unsigned short h) {
  return __uint_as_float(((unsigned)h) << 16);
}

// numpy pairwise sum of squares (n=256): two 128-blocks of 8 accumulators.
__device__ __forceinline__ float pw128_sq(const float* p, int s) {
  float r[8];
#pragma unroll
  for (int j = 0; j < 8; ++j) { float v = p[j * s]; r[j] = __fmul_rn(v, v); }
#pragma unroll
  for (int i = 8; i < 128; i += 8) {
#pragma unroll
    for (int j = 0; j < 8; ++j) {
      float v = p[(i + j) * s];
      r[j] = __fadd_rn(r[j], __fmul_rn(v, v));
    }
  }
  return __fadd_rn(__fadd_rn(__fadd_rn(r[0], r[1]), __fadd_rn(r[2], r[3])),
                   __fadd_rn(__fadd_rn(r[4], r[5]), __fadd_rn(r[6], r[7])));
}
__device__ __forceinline__ float np_sumsq256(const float* p, int s) {
  return __fadd_rn(pw128_sq(p, s), pw128_sq(p + 128 * s, s));
}

// ---- prep (LDS transpose): 64 blocks, block b owns codes [b*16, b*16+16) ----
// Produces: cbimg tile T=b (fp16 x1024, frag layout: short idx T*4096 + kk*512
// + (lk*16+jj)*8 + m for code j=T*16+jj, c=kk*32+lk*8+m), np-exact Bsg, and
// cbT[c][j] stripe (16 consecutive floats per c -> line-efficient stores).
__global__ __launch_bounds__(256)
void vq_prep(const float* __restrict__ cb, unsigned short* __restrict__ cbimg,
             float* __restrict__ cbT, float* __restrict__ Bsg,
             unsigned* __restrict__ cnt, float* __restrict__ loss) {
  __shared__ float rows[16][260];
  const int t = threadIdx.x;
  const int b = blockIdx.x;            // tile T = b
  if (b == 0 && t == 0) { cnt[0] = 0u; *loss = 0.0f; }
  // stage 16 codebook rows, coalesced float4
#pragma unroll
  for (int i = 0; i < 4; ++i) {
    int idx = t + i * 256;             // r = idx>>6, c4 = idx&63
    int r = idx >> 6, c4 = idx & 63;
    float4 v = reinterpret_cast<const float4*>(cb + (size_t)(b * 16 + r) * 256)[c4];
    rows[r][c4 * 4 + 0] = v.x;
    rows[r][c4 * 4 + 1] = v.y;
    rows[r][c4 * 4 + 2] = v.z;
    rows[r][c4 * 4 + 3] = v.w;
  }
  __syncthreads();
  if (t < 16) Bsg[b * 16 + t] = np_sumsq256(&rows[t][0], 1);
  // cbimg: 512 s16x8 units per tile; thread writes units 2t, 2t+1
#pragma unroll
  for (int uu = 0; uu < 2; ++uu) {
    int u = t * 2 + uu;
    int kk = u >> 6, rem = u & 63;
    int lk = rem >> 4, jj = rem & 15;
    int c0 = kk * 32 + lk * 8;
    s16x8 hv;
#pragma unroll
    for (int m = 0; m < 8; ++m)
      hv[m] = (short)__half_as_ushort(__float2half(rows[jj][c0 + m] * 1024.0f));
    *reinterpret_cast<s16x8*>(cbimg + (size_t)b * 4096 + u * 8) = hv;
  }
  // cbT stripe: thread t = column c, writes 16 consecutive floats
  {
    float* dst = cbT + (size_t)t * 1024 + b * 16;
#pragma unroll
    for (int jj = 0; jj < 16; ++jj) dst[jj] = rows[jj][t];
  }
}

// one 16-code tile: 8 kk MFMA x 4 row-subtiles + top-2 update; next tile's
// B-frag load issued right after ba[kk] is consumed (~28 MFMAs of cover).
// Macro (not lambda) so no register array is address-taken (rule #20).
#define VQ_STEP_PF(IT2, DO_PF)                                                 \
  {                                                                            \
    f32x4 acc[4];                                                              \
    _Pragma("unroll")                                                          \
    for (int rs = 0; rs < 4; ++rs) acc[rs] = (f32x4){0.f, 0.f, 0.f, 0.f};      \
    _Pragma("unroll")                                                          \
    for (int kk = 0; kk < 8; ++kk) {                                           \
      f16x8 bcur = ba[kk];                                                     \
      if (DO_PF)                                                               \
        ba[kk] = cimg2[(size_t)(wv * 16 + (IT2) + 1) * 512 + kk * 64 + lane];  \
      _Pragma("unroll")                                                        \
      for (int rs = 0; rs < 4; ++rs)                                           \
        acc[rs] = __builtin_amdgcn_mfma_f32_16x16x32_f16(ah[rs][kk], bcur,     \
                                                         acc[rs], 0, 0, 0);    \
    }                                                                          \
    int j = wv * 256 + (IT2) * 16 + l15;                                       \
    float Bj = BsL[j];                                                         \
    _Pragma("unroll")                                                          \
    for (int rs = 0; rs < 4; ++rs) {                                           \
      _Pragma("unroll")                                                        \
      for (int r = 0; r < 4; ++r) {                                            \
        float s = fmaf(SCORE_SCALE, acc[rs][r], Bj);                           \
        bool lt = s < b1v[rs][r];                                              \
        float other = lt ? b1v[rs][r] : s;                                     \
        b2v[rs][r] = fminf(b2v[rs][r], other);                                 \
        b1v[rs][r] = fminf(b1v[rs][r], s);                                     \
        b1i[rs][r] = lt ? j : b1i[rs][r];                                      \
      }                                                                        \
    }                                                                          \
  }

// ---- fast: 512 blocks x 64 rows, 4 waves code-partitioned, B global->reg ----
// (256,1) + padded LDS (~72 KB -> exactly 2 blocks/CU) pins the allocator at
// a 256-VGPR budget so the 128-VGPR ah stays in registers (r13 verified: 168).
__global__ __launch_bounds__(256, 1)
void vq_fast(const float* __restrict__ z, const float* __restrict__ cb,
             const unsigned short* __restrict__ cbimg,
             const float* __restrict__ Bsg,
             float* __restrict__ zq, float* __restrict__ loss,
             float* __restrict__ idxo,
             unsigned* __restrict__ list, unsigned* __restrict__ cnt,
             float* __restrict__ zdump) {
  __shared__ __align__(16) unsigned char buf[58880]; // zt / epilogue ldsF; padded (occupancy pin)
  __shared__ float BsL[1024];
  __shared__ float part[32][36];
  __shared__ float rowA[64];
  __shared__ int bestj[64];
  __shared__ float bestd[64];
  __shared__ unsigned char flg[64];
  __shared__ float wred[4];
  __shared__ float cv1[4 * 64], cv2[4 * 64];
  __shared__ int ci1[4 * 64];

  const int t = threadIdx.x;
  const int bid = blockIdx.x;          // = bh; rows n0 = bid*64
  const int lane = t & 63;
  const int wv = t >> 6;               // wave 0..3: codes wv*256..+255
  const int l15 = lane & 15;
  const int lk = lane >> 4;            // 0..3

  const f16x8* cimg2 = reinterpret_cast<const f16x8*>(cbimg);  // 16B units
  float* zt = reinterpret_cast<float*>(buf);   // [256 c][33] f32 during A-stage
  const float4* z4 = reinterpret_cast<const float4*>(
      z + (size_t)(bid >> 6) * 1048576 + (size_t)(bid & 63) * 64);

  // issue tile-0 loads of this wave's quarter early (latency under A-stage)
  f16x8 ba[8];
#pragma unroll
  for (int kk = 0; kk < 8; ++kk)
    ba[kk] = cimg2[(size_t)(wv * 16) * 512 + kk * 64 + lane];

  for (int i = t; i < 1024; i += 256) BsL[i] = Bsg[i];

  f16x8 ah[4][8];                      // all 64 rows: 4 subtiles x 8 k-steps
  // ---- A staging in halves of 32 rows (UNROLLED: ah indices static) ----
#pragma unroll
  for (int hp = 0; hp < 2; ++hp) {
    float sq[4] = {0.f, 0.f, 0.f, 0.f};
#pragma unroll
    for (int i = 0; i < 8; ++i) {
      int idx = t + i * 256;           // c = idx>>3, w4p = idx&7
      int c = idx >> 3, w4p = idx & 7;
      float4 v = z4[(size_t)c * 1024 + hp * 8 + w4p];
      zt[c * 33 + w4p * 4 + 0] = v.x;
      zt[c * 33 + w4p * 4 + 1] = v.y;
      zt[c * 33 + w4p * 4 + 2] = v.z;
      zt[c * 33 + w4p * 4 + 3] = v.w;
      sq[0] += v.x * v.x; sq[1] += v.y * v.y;
      sq[2] += v.z * v.z; sq[3] += v.w * v.w;
    }
#pragma unroll
    for (int q = 0; q < 4; ++q) part[t >> 3][(t & 7) * 4 + q] = sq[q];
    __syncthreads();
    if (t < 32) {
      float s = 0.f;
#pragma unroll
      for (int g = 0; g < 32; ++g) s += part[g][t];
      rowA[hp * 32 + t] = s;
    }
    // every wave loads a-frags for BOTH row-subtiles of this half (fp16 RNE)
#pragma unroll
    for (int rr2 = 0; rr2 < 2; ++rr2) {
      int lr = rr2 * 16 + l15;         // row within half
#pragma unroll
      for (int kk = 0; kk < 8; ++kk)
#pragma unroll
        for (int m = 0; m < 8; ++m)
          ah[hp * 2 + rr2][kk][m] = (_Float16)zt[(kk * 32 + lk * 8 + m) * 33 + lr];
    }
    // z-dump (coalesced [n][c]) for the exact pass
#pragma unroll
    for (int i = 0; i < 8; ++i) {
      int item = t + i * 256;          // c4 = item&63, rowp = item>>6 in [0,32)
      int c4 = item & 63, rowp = item >> 6;
      float4 v = make_float4(zt[(c4 * 4 + 0) * 33 + rowp],
                             zt[(c4 * 4 + 1) * 33 + rowp],
                             zt[(c4 * 4 + 2) * 33 + rowp],
                             zt[(c4 * 4 + 3) * 33 + rowp]);
      *reinterpret_cast<float4*>(
          zdump + ((size_t)bid * 64 + hp * 32 + rowp) * 256 + c4 * 4) = v;
    }
    __syncthreads();
  }

  float b1v[4][4], b2v[4][4];
  int b1i[4][4];
#pragma unroll
  for (int rs = 0; rs < 4; ++rs)
#pragma unroll
    for (int r = 0; r < 4; ++r) { b1v[rs][r] = 3.4e38f; b2v[rs][r] = 3.4e38f; b1i[rs][r] = 0; }

  // barrier-free main loop over this wave's 16 private tiles
  for (int it = 0; it < 15; ++it) {
    VQ_STEP_PF(it, true);
  }
  VQ_STEP_PF(15, false);

  // ---- merge top-2 across the 16 lanes sharing rows (within wave) ----
#pragma unroll
  for (int mk = 1; mk < 16; mk <<= 1) {
#pragma unroll
    for (int rs = 0; rs < 4; ++rs)
#pragma unroll
      for (int r = 0; r < 4; ++r) {
        float ov1 = __shfl_xor(b1v[rs][r], mk, 64);
        float ov2 = __shfl_xor(b2v[rs][r], mk, 64);
        int oi1 = __shfl_xor(b1i[rs][r], mk, 64);
        bool lt = ov1 < b1v[rs][r];
        float hi = lt ? b1v[rs][r] : ov1;
        b2v[rs][r] = fminf(fminf(b2v[rs][r], ov2), hi);
        b1v[rs][r] = fminf(b1v[rs][r], ov1);
        b1i[rs][r] = lt ? oi1 : b1i[rs][r];
      }
  }
  if (l15 == 0) {
#pragma unroll
    for (int rs = 0; rs < 4; ++rs)
#pragma unroll
      for (int r = 0; r < 4; ++r) {
        int rr = rs * 16 + lk * 4 + r;     // D row = (lane>>4)*4 + reg
        cv1[wv * 64 + rr] = b1v[rs][r];
        cv2[wv * 64 + rr] = b2v[rs][r];
        ci1[wv * 64 + rr] = b1i[rs][r];
      }
  }
  __syncthreads();

  // ---- cross-wave merge (wave order = ascending code ranges) ----
  if (t < 64) {
    float v1 = cv1[t], v2 = cv2[t];
    int i1 = ci1[t];
#pragma unroll
    for (int w = 1; w < 4; ++w) {
      float u1 = cv1[w * 64 + t], u2 = cv2[w * 64 + t];
      int ui = ci1[w * 64 + t];
      if (u1 < v1) { v2 = fminf(v1, u2); v1 = u1; i1 = ui; }
      else v2 = fminf(v2, u1);
    }
    bestj[t] = i1;
    bestd[t] = v1;
    flg[t] = (v2 - v1 <= M_GAP) ? 1 : 0;
    int n = bid * 64 + t;
    idxo[n] = (float)i1;               // provisional for flagged rows
    if (flg[t]) { unsigned pos = atomicAdd(cnt, 1u); list[pos] = (unsigned)n; }
  }
  __syncthreads();

  // loss over ALL rows (flagged rows' provisional s_best within tolerance)
  {
    float lv = (t < 64) ? (rowA[t] + bestd[t]) : 0.f;
#pragma unroll
    for (int off = 32; off > 0; off >>= 1) lv += __shfl_down(lv, off, 64);
    if (lane == 0) wred[wv] = lv;
  }
  __syncthreads();
  if (t == 0)
    atomicAdd(loss, (wred[0] + wred[1] + wred[2] + wred[3]) * (1.25f / (float)NELEM));

  // ---- zq gather in halves: cb rows -> LDS transpose -> coalesced write ----
  f32x4* ldsF4 = reinterpret_cast<f32x4*>(buf);
  const float* ldsF = reinterpret_cast<const float*>(buf);
  const float4* cb4 = reinterpret_cast<const float4*>(cb);
  float* zqb = zq + (size_t)(bid >> 6) * 1048576 + (size_t)(bid & 63) * 64;
  for (int hp = 0; hp < 2; ++hp) {
    __syncthreads();
#pragma unroll
    for (int i = 0; i < 8; ++i) {
      int item = t + i * 256;            // rr = item>>6 in [0,32), cc = item&63
      int rr = item >> 6, cc = item & 63;
      float4 v = cb4[(size_t)bestj[hp * 32 + rr] * 64 + cc];
      ldsF4[rr * 64 + (cc ^ ((rr >> 2) & 7))] = (f32x4){v.x, v.y, v.z, v.w};
    }
    __syncthreads();
#pragma unroll
    for (int i = 0; i < 8; ++i) {
      int item = t + i * 256;            // w4p = item&7, c = item>>3
      int w4p = item & 7, c = item >> 3;
      float ov[4];
#pragma unroll
      for (int q = 0; q < 4; ++q) {
        int rr = w4p * 4 + q;
        ov[q] = ldsF[(rr * 64 + ((c >> 2) ^ ((rr >> 2) & 7))) * 4 + (c & 3)];
      }
      *reinterpret_cast<float4*>(zqb + (size_t)c * 4096 + hp * 32 + w4p * 4) =
          make_float4(ov[0], ov[1], ov[2], ov[3]);
    }
  }
}

// ---- exact rescore: batched 8 rows, coalesced zdump + cbT, idx-only ----
__global__ __launch_bounds__(256)
void vq_exact_fast(const float* __restrict__ zdump, const float* __restrict__ cbT,
                   const float* __restrict__ Bsg, const unsigned* __restrict__ list,
                   const unsigned* __restrict__ cnt, float* __restrict__ idxo) {
  __shared__ float zr[8][260];
  __shared__ float Anp[8];
  __shared__ float rv[256];
  __shared__ int ri[256];
  const int t = threadIdx.x;
  const unsigned K = *cnt;
  const float4* cbT4 = reinterpret_cast<const float4*>(cbT);
  const float4* zd4 = reinterpret_cast<const float4*>(zdump);

  for (unsigned g = blockIdx.x; g * 8 < K; g += gridDim.x) {
    int nrows = (int)min(8u, K - g * 8);
    __syncthreads();
#pragma unroll
    for (int i = 0; i < 2; ++i) {
      int idx = t + i * 256;             // r = idx>>6, c4 = idx&63
      int r = idx >> 6, c4 = idx & 63;
      if (r < nrows) {
        float4 v = zd4[(size_t)list[g * 8 + r] * 64 + c4];
        zr[r][c4 * 4 + 0] = v.x; zr[r][c4 * 4 + 1] = v.y;
        zr[r][c4 * 4 + 2] = v.z; zr[r][c4 * 4 + 3] = v.w;
      }
    }
    __syncthreads();
    if (t < nrows) Anp[t] = np_sumsq256(&zr[t][0], 1);
    __syncthreads();

    float acc[8][4];
#pragma unroll
    for (int r = 0; r < 8; ++r)
#pragma unroll
      for (int q = 0; q < 4; ++q) acc[r][q] = 0.f;
    for (int c = 0; c < 256; ++c) {
      float4 bv = cbT4[c * 256 + t];
#pragma unroll
      for (int r = 0; r < 8; ++r) {
        float zc = zr[r][c];
        acc[r][0] = fmaf(zc, bv.x, acc[r][0]);
        acc[r][1] = fmaf(zc, bv.y, acc[r][1]);
        acc[r][2] = fmaf(zc, bv.z, acc[r][2]);
        acc[r][3] = fmaf(zc, bv.w, acc[r][3]);
      }
    }
    for (int r = 0; r < nrows; ++r) {
      float A = Anp[r];
      float bvv = 3.4e38f;
      int bii = 0;
#pragma unroll
      for (int q = 0; q < 4; ++q) {
        int j = t * 4 + q;
        float dd = __fsub_rn(__fadd_rn(A, Bsg[j]), __fmul_rn(2.0f, acc[r][q]));
        if (dd < bvv) { bvv = dd; bii = j; }
      }
      rv[t] = bvv; ri[t] = bii;
      __syncthreads();
      for (int s2 = 128; s2 > 0; s2 >>= 1) {
        if (t < s2) {
          float v2 = rv[t + s2]; int i2 = ri[t + s2];
          if (v2 < rv[t] || (v2 == rv[t] && i2 < ri[t])) { rv[t] = v2; ri[t] = i2; }
        }
        __syncthreads();
      }
      if (t == 0) idxo[list[g * 8 + r]] = (float)ri[0];
      __syncthreads();
    }
  }
}

// ---- fallback (round-2 validated all-exact kernel) ----
__global__ __launch_bounds__(256)
void vq_ref(const float* __restrict__ z, const float* __restrict__ cb,
            float* __restrict__ zq, float* __restrict__ loss,
            float* __restrict__ idxo) {
  __shared__ __align__(16) float zt[256 * 64];
  __shared__ __align__(16) float cbt[256 * 64];
  __shared__ float As[64];
  __shared__ float Bs[64];
  __shared__ int bestj[64];
  __shared__ float cand_v[16 * 64];
  __shared__ int cand_i[16 * 64];
  __shared__ double wred[4];
  const int t = threadIdx.x;
  const int wg = t & 15, jg = t >> 4;
  const int bid = blockIdx.x;
  const int b = bid >> 6, h = bid & 63;
  const int n0 = bid * 64;
  const float4* z4 = reinterpret_cast<const float4*>(z + (size_t)b * 256 * 4096 + (size_t)h * 64);
  float4* zt4 = reinterpret_cast<float4*>(zt);
#pragma unroll
  for (int i = 0; i < 16; ++i) {
    int idx4 = t + i * 256;
    zt4[idx4] = z4[(size_t)(idx4 >> 4) * 1024 + (idx4 & 15)];
  }
  __syncthreads();
  if (t < 64) As[t] = np_sumsq256(zt + t, 64);
  float bv[4]; int bi[4];
#pragma unroll
  for (int a = 0; a < 4; ++a) { bv[a] = 3.4e38f; bi[a] = 0; }
  for (int p = 0; p < 16; ++p) {
    __syncthreads();
    const float4* cb4 = reinterpret_cast<const float4*>(cb) + (size_t)p * 64 * 64;
#pragma unroll
    for (int i = 0; i < 16; ++i) {
      int idx4 = t + i * 256;
      int jj = idx4 >> 6, c4 = idx4 & 63;
      float4 v = cb4[idx4];
      cbt[(c4 * 4 + 0) * 64 + jj] = v.x;
      cbt[(c4 * 4 + 1) * 64 + jj] = v.y;
      cbt[(c4 * 4 + 2) * 64 + jj] = v.z;
      cbt[(c4 * 4 + 3) * 64 + jj] = v.w;
    }
    __syncthreads();
    if (t < 64) Bs[t] = np_sumsq256(cbt + t, 64);
    float acc[4][4];
#pragma unroll
    for (int a = 0; a < 4; ++a)
#pragma unroll
      for (int u = 0; u < 4; ++u) acc[a][u] = 0.0f;
    const float4* ztp = reinterpret_cast<const float4*>(zt) + wg;
    const float4* cbp = reinterpret_cast<const float4*>(cbt) + jg;
#pragma unroll 4
    for (int c = 0; c < 256; ++c) {
      float4 zv = ztp[c * 16];
      float4 cv = cbp[c * 16];
      float za[4] = {zv.x, zv.y, zv.z, zv.w};
      float ca[4] = {cv.x, cv.y, cv.z, cv.w};
#pragma unroll
      for (int a = 0; a < 4; ++a)
#pragma unroll
        for (int u = 0; u < 4; ++u) acc[a][u] = fmaf(za[a], ca[u], acc[a][u]);
    }
    __syncthreads();
#pragma unroll
    for (int u = 0; u < 4; ++u) {
      int j = p * 64 + jg * 4 + u;
      float Bju = Bs[jg * 4 + u];
#pragma unroll
      for (int a = 0; a < 4; ++a) {
        float AB = __fadd_rn(As[wg * 4 + a], Bju);
        float dd = __fsub_rn(AB, __fmul_rn(2.0f, acc[a][u]));
        if (dd < bv[a]) { bv[a] = dd; bi[a] = j; }
      }
    }
  }
  __syncthreads();
#pragma unroll
  for (int a = 0; a < 4; ++a) {
    int w = wg * 4 + a;
    cand_v[jg * 64 + w] = bv[a];
    cand_i[jg * 64 + w] = bi[a];
  }
  __syncthreads();
  if (t < 64) {
    float v0 = cand_v[t]; int i0 = cand_i[t];
    for (int g = 1; g < 16; ++g) {
      float v = cand_v[g * 64 + t]; int ii = cand_i[g * 64 + t];
      if (v < v0 || (v == v0 && ii < i0)) { v0 = v; i0 = ii; }
    }
    bestj[t] = i0;
    idxo[n0 + t] = (float)i0;
  }
  __syncthreads();
  double lsum = 0.0;
  float* zqbase = zq + (size_t)b * 256 * 4096 + (size_t)h * 64;
  for (int i = 0; i < 64; ++i) {
    int idx = t + i * 256;
    int c = idx >> 6, w = idx & 63;
    float zvv = zt[c * 64 + w];
    float cvv = cb[(size_t)bestj[w] * 256 + c];
    zqbase[(size_t)c * 4096 + w] = cvv;
    double d = (double)cvv - (double)zvv;
    lsum += d * d;
  }
#pragma unroll
  for (int off = 32; off > 0; off >>= 1) lsum += __shfl_down(lsum, off, 64);
  if ((t & 63) == 0) wred[t >> 6] = lsum;
  __syncthreads();
  if (t == 0) {
    double tot = wred[0] + wred[1] + wred[2] + wred[3];
    atomicAdd(loss, (float)(tot * (1.25 / (double)NELEM)));
  }
}

extern "C" void kernel_launch(void* const* d_in, const int* in_sizes, int n_in,
                              void* d_out, int out_size, void* d_ws, size_t ws_size,
                              hipStream_t stream) {
  (void)in_sizes; (void)n_in; (void)out_size;
  const float* z = (const float*)d_in[0];
  const float* cb = (const float*)d_in[1];
  float* out = (float*)d_out;
  float* zq = out;
  float* loss = out + NELEM;
  float* idxo = out + NELEM + 1;
  if (ws_size < 35651584) {  // need zdump: else validated all-exact path
    hipMemsetAsync(loss, 0, sizeof(float), stream);
    vq_ref<<<512, 256, 0, stream>>>(z, cb, zq, loss, idxo);
    return;
  }
  unsigned char* ws = (unsigned char*)d_ws;
  unsigned* cnt = (unsigned*)ws;                             // 4 B
  float* Bsg = (float*)(ws + 1024);                          // 4 KB
  unsigned* list = (unsigned*)(ws + 8192);                   // 128 KB
  float* cbT = (float*)(ws + 139264);                        // 1 MB
  unsigned short* cbimg = (unsigned short*)(ws + 1187840);   // 512 KB fp16 frag-layout
  float* zdump = (float*)(ws + 2097152);                     // 32 MB
  vq_prep<<<64, 256, 0, stream>>>(cb, cbimg, cbT, Bsg, cnt, loss);
  vq_fast<<<512, 256, 0, stream>>>(z, cb, cbimg, Bsg, zq, loss, idxo, list, cnt, zdump);
  vq_exact_fast<<<512, 256, 0, stream>>>(zdump, cbT, Bsg, list, cnt, idxo);
}

// Round 16
// 98.890 us; speedup vs baseline: 1.4879x; 1.0181x over previous
//
#include <hip/hip_runtime.h>
#include <hip/hip_fp16.h>

#define NELEM 8388608    // 8*256*64*64
#define M_GAP 6e-4f      // validated rounds 6/8/9/13 (fp16 1-plane, x1024 codebook)
#define SCORE_SCALE (-1.0f / 512.0f)

typedef _Float16 f16x8 __attribute__((ext_vector_type(8)));
typedef short s16x8 __attribute__((ext_vector_type(8)));
typedef float f32x4 __attribute__((ext_vector_type(4)));

__device__ __forceinline__ unsigned short bf16r(float f) {
  unsigned u = __float_as_uint(f);
  return (unsigned short)((u + 0x7fffu + ((u >> 16) & 1u)) >> 16);
}
__device__ __forceinline__ float bf16f(unsigned short h) {
  return __uint_as_float(((unsigned)h) << 16);
}

// numpy pairwise sum of squares (n=256): two 128-blocks of 8 accumulators.
__device__ __forceinline__ float pw128_sq(const float* p, int s) {
  float r[8];
#pragma unroll
  for (int j = 0; j < 8; ++j) { float v = p[j * s]; r[j] = __fmul_rn(v, v); }
#pragma unroll
  for (int i = 8; i < 128; i += 8) {
#pragma unroll
    for (int j = 0; j < 8; ++j) {
      float v = p[(i + j) * s];
      r[j] = __fadd_rn(r[j], __fmul_rn(v, v));
    }
  }
  return __fadd_rn(__fadd_rn(__fadd_rn(r[0], r[1]), __fadd_rn(r[2], r[3])),
                   __fadd_rn(__fadd_rn(r[4], r[5]), __fadd_rn(r[6], r[7])));
}
__device__ __forceinline__ float np_sumsq256(const float* p, int s) {
  return __fadd_rn(pw128_sq(p, s), pw128_sq(p + 128 * s, s));
}

// ---- prep (LDS transpose): 64 blocks, block b owns codes [b*16, b*16+16) ----
__global__ __launch_bounds__(256)
void vq_prep(const float* __restrict__ cb, unsigned short* __restrict__ cbimg,
             float* __restrict__ cbT, float* __restrict__ Bsg,
             unsigned* __restrict__ cnt, float* __restrict__ loss) {
  __shared__ float rows[16][260];
  const int t = threadIdx.x;
  const int b = blockIdx.x;            // tile T = b
  if (b == 0 && t == 0) { cnt[0] = 0u; *loss = 0.0f; }
#pragma unroll
  for (int i = 0; i < 4; ++i) {
    int idx = t + i * 256;             // r = idx>>6, c4 = idx&63
    int r = idx >> 6, c4 = idx & 63;
    float4 v = reinterpret_cast<const float4*>(cb + (size_t)(b * 16 + r) * 256)[c4];
    rows[r][c4 * 4 + 0] = v.x;
    rows[r][c4 * 4 + 1] = v.y;
    rows[r][c4 * 4 + 2] = v.z;
    rows[r][c4 * 4 + 3] = v.w;
  }
  __syncthreads();
  if (t < 16) Bsg[b * 16 + t] = np_sumsq256(&rows[t][0], 1);
  // cbimg frag layout: short idx T*4096 + kk*512 + (lk*16+jj)*8 + m
#pragma unroll
  for (int uu = 0; uu < 2; ++uu) {
    int u = t * 2 + uu;
    int kk = u >> 6, rem = u & 63;
    int lk = rem >> 4, jj = rem & 15;
    int c0 = kk * 32 + lk * 8;
    s16x8 hv;
#pragma unroll
    for (int m = 0; m < 8; ++m)
      hv[m] = (short)__half_as_ushort(__float2half(rows[jj][c0 + m] * 1024.0f));
    *reinterpret_cast<s16x8*>(cbimg + (size_t)b * 4096 + u * 8) = hv;
  }
  // cbT stripe: thread t = column c, 16 consecutive floats (line-efficient)
  {
    float* dst = cbT + (size_t)t * 1024 + b * 16;
#pragma unroll
    for (int jj = 0; jj < 16; ++jj) dst[jj] = rows[jj][t];
  }
}

// one 16-code tile: 8 kk MFMA x 4 row-subtiles + top-2 update; next tile's
// B-frag load issued right after ba[kk] is consumed (~28 MFMAs of cover).
// Macro (not lambda) so no register array is address-taken (rule #20).
#define VQ_STEP_PF(IT2, DO_PF)                                                 \
  {                                                                            \
    f32x4 acc[4];                                                              \
    _Pragma("unroll")                                                          \
    for (int rs = 0; rs < 4; ++rs) acc[rs] = (f32x4){0.f, 0.f, 0.f, 0.f};      \
    _Pragma("unroll")                                                          \
    for (int kk = 0; kk < 8; ++kk) {                                           \
      f16x8 bcur = ba[kk];                                                     \
      if (DO_PF)                                                               \
        ba[kk] = cimg2[(size_t)(wv * 16 + (IT2) + 1) * 512 + kk * 64 + lane];  \
      _Pragma("unroll")                                                        \
      for (int rs = 0; rs < 4; ++rs)                                           \
        acc[rs] = __builtin_amdgcn_mfma_f32_16x16x32_f16(ah[rs][kk], bcur,     \
                                                         acc[rs], 0, 0, 0);    \
    }                                                                          \
    int j = wv * 256 + (IT2) * 16 + l15;                                       \
    float Bj = BsL[j];                                                         \
    _Pragma("unroll")                                                          \
    for (int rs = 0; rs < 4; ++rs) {                                           \
      _Pragma("unroll")                                                        \
      for (int r = 0; r < 4; ++r) {                                            \
        float s = fmaf(SCORE_SCALE, acc[rs][r], Bj);                           \
        bool lt = s < b1v[rs][r];                                              \
        float other = lt ? b1v[rs][r] : s;                                     \
        b2v[rs][r] = fminf(b2v[rs][r], other);                                 \
        b1v[rs][r] = fminf(b1v[rs][r], s);                                     \
        b1i[rs][r] = lt ? j : b1i[rs][r];                                      \
      }                                                                        \
    }                                                                          \
  }

// ---- fast: 512 blocks x 64 rows, 4 waves code-partitioned, B global->reg ----
// (256,1) + 47.6 KB LDS: 2 blocks/CU resident (multi-block LDS pool ~128 KB),
// heuristic allocator picks ~156-172 VGPR (no spill, r13-verified with (256,1)).
__global__ __launch_bounds__(256, 1)
void vq_fast(const float* __restrict__ z, const float* __restrict__ cb,
             const unsigned short* __restrict__ cbimg,
             const float* __restrict__ Bsg,
             float* __restrict__ zq, float* __restrict__ loss,
             float* __restrict__ idxo,
             unsigned* __restrict__ list, unsigned* __restrict__ cnt,
             float* __restrict__ zdump) {
  __shared__ __align__(16) unsigned char buf[34816]; // zt[256][33] f32 / epilogue ldsF
  __shared__ float BsL[1024];
  __shared__ float part[32][36];
  __shared__ float rowA[64];
  __shared__ int bestj[64];
  __shared__ float bestd[64];
  __shared__ unsigned char flg[64];
  __shared__ float wred[4];
  __shared__ float cv1[4 * 64], cv2[4 * 64];
  __shared__ int ci1[4 * 64];

  const int t = threadIdx.x;
  const int bid = blockIdx.x;          // = bh; rows n0 = bid*64
  const int lane = t & 63;
  const int wv = t >> 6;               // wave 0..3: codes wv*256..+255
  const int l15 = lane & 15;
  const int lk = lane >> 4;            // 0..3

  const f16x8* cimg2 = reinterpret_cast<const f16x8*>(cbimg);  // 16B units
  float* zt = reinterpret_cast<float*>(buf);   // [256 c][33] f32 during A-stage
  const float4* z4 = reinterpret_cast<const float4*>(
      z + (size_t)(bid >> 6) * 1048576 + (size_t)(bid & 63) * 64);

  // issue tile-0 loads of this wave's quarter early (latency under A-stage)
  f16x8 ba[8];
#pragma unroll
  for (int kk = 0; kk < 8; ++kk)
    ba[kk] = cimg2[(size_t)(wv * 16) * 512 + kk * 64 + lane];

  for (int i = t; i < 1024; i += 256) BsL[i] = Bsg[i];

  f16x8 ah[4][8];                      // all 64 rows: 4 subtiles x 8 k-steps
  // ---- A staging in halves of 32 rows (UNROLLED: ah indices static) ----
#pragma unroll
  for (int hp = 0; hp < 2; ++hp) {
    float sq[4] = {0.f, 0.f, 0.f, 0.f};
#pragma unroll
    for (int i = 0; i < 8; ++i) {
      int idx = t + i * 256;           // c = idx>>3, w4p = idx&7
      int c = idx >> 3, w4p = idx & 7;
      float4 v = z4[(size_t)c * 1024 + hp * 8 + w4p];
      zt[c * 33 + w4p * 4 + 0] = v.x;
      zt[c * 33 + w4p * 4 + 1] = v.y;
      zt[c * 33 + w4p * 4 + 2] = v.z;
      zt[c * 33 + w4p * 4 + 3] = v.w;
      sq[0] += v.x * v.x; sq[1] += v.y * v.y;
      sq[2] += v.z * v.z; sq[3] += v.w * v.w;
    }
#pragma unroll
    for (int q = 0; q < 4; ++q) part[t >> 3][(t & 7) * 4 + q] = sq[q];
    __syncthreads();
    if (t < 32) {
      float s = 0.f;
#pragma unroll
      for (int g = 0; g < 32; ++g) s += part[g][t];
      rowA[hp * 32 + t] = s;
    }
    // every wave loads a-frags for BOTH row-subtiles of this half (fp16 RNE)
#pragma unroll
    for (int rr2 = 0; rr2 < 2; ++rr2) {
      int lr = rr2 * 16 + l15;         // row within half
#pragma unroll
      for (int kk = 0; kk < 8; ++kk)
#pragma unroll
        for (int m = 0; m < 8; ++m)
          ah[hp * 2 + rr2][kk][m] = (_Float16)zt[(kk * 32 + lk * 8 + m) * 33 + lr];
    }
    // z-dump (coalesced [n][c]) for the exact pass
#pragma unroll
    for (int i = 0; i < 8; ++i) {
      int item = t + i * 256;          // c4 = item&63, rowp = item>>6 in [0,32)
      int c4 = item & 63, rowp = item >> 6;
      float4 v = make_float4(zt[(c4 * 4 + 0) * 33 + rowp],
                             zt[(c4 * 4 + 1) * 33 + rowp],
                             zt[(c4 * 4 + 2) * 33 + rowp],
                             zt[(c4 * 4 + 3) * 33 + rowp]);
      *reinterpret_cast<float4*>(
          zdump + ((size_t)bid * 64 + hp * 32 + rowp) * 256 + c4 * 4) = v;
    }
    __syncthreads();
  }

  float b1v[4][4], b2v[4][4];
  int b1i[4][4];
#pragma unroll
  for (int rs = 0; rs < 4; ++rs)
#pragma unroll
    for (int r = 0; r < 4; ++r) { b1v[rs][r] = 3.4e38f; b2v[rs][r] = 3.4e38f; b1i[rs][r] = 0; }

  // barrier-free main loop over this wave's 16 private tiles
  for (int it = 0; it < 15; ++it) {
    VQ_STEP_PF(it, true);
  }
  VQ_STEP_PF(15, false);

  // ---- merge top-2 across the 16 lanes sharing rows (within wave) ----
#pragma unroll
  for (int mk = 1; mk < 16; mk <<= 1) {
#pragma unroll
    for (int rs = 0; rs < 4; ++rs)
#pragma unroll
      for (int r = 0; r < 4; ++r) {
        float ov1 = __shfl_xor(b1v[rs][r], mk, 64);
        float ov2 = __shfl_xor(b2v[rs][r], mk, 64);
        int oi1 = __shfl_xor(b1i[rs][r], mk, 64);
        bool lt = ov1 < b1v[rs][r];
        float hi = lt ? b1v[rs][r] : ov1;
        b2v[rs][r] = fminf(fminf(b2v[rs][r], ov2), hi);
        b1v[rs][r] = fminf(b1v[rs][r], ov1);
        b1i[rs][r] = lt ? oi1 : b1i[rs][r];
      }
  }
  if (l15 == 0) {
#pragma unroll
    for (int rs = 0; rs < 4; ++rs)
#pragma unroll
      for (int r = 0; r < 4; ++r) {
        int rr = rs * 16 + lk * 4 + r;     // D row = (lane>>4)*4 + reg
        cv1[wv * 64 + rr] = b1v[rs][r];
        cv2[wv * 64 + rr] = b2v[rs][r];
        ci1[wv * 64 + rr] = b1i[rs][r];
      }
  }
  __syncthreads();

  // ---- cross-wave merge (wave order = ascending code ranges) ----
  if (t < 64) {
    float v1 = cv1[t], v2 = cv2[t];
    int i1 = ci1[t];
#pragma unroll
    for (int w = 1; w < 4; ++w) {
      float u1 = cv1[w * 64 + t], u2 = cv2[w * 64 + t];
      int ui = ci1[w * 64 + t];
      if (u1 < v1) { v2 = fminf(v1, u2); v1 = u1; i1 = ui; }
      else v2 = fminf(v2, u1);
    }
    bestj[t] = i1;
    bestd[t] = v1;
    flg[t] = (v2 - v1 <= M_GAP) ? 1 : 0;
    int n = bid * 64 + t;
    idxo[n] = (float)i1;               // provisional for flagged rows
    if (flg[t]) { unsigned pos = atomicAdd(cnt, 1u); list[pos] = (unsigned)n; }
  }
  __syncthreads();

  // loss over ALL rows (flagged rows' provisional s_best within tolerance)
  {
    float lv = (t < 64) ? (rowA[t] + bestd[t]) : 0.f;
#pragma unroll
    for (int off = 32; off > 0; off >>= 1) lv += __shfl_down(lv, off, 64);
    if (lane == 0) wred[wv] = lv;
  }
  __syncthreads();
  if (t == 0)
    atomicAdd(loss, (wred[0] + wred[1] + wred[2] + wred[3]) * (1.25f / (float)NELEM));

  // ---- zq gather in halves: cb rows -> LDS transpose -> coalesced write ----
  f32x4* ldsF4 = reinterpret_cast<f32x4*>(buf);
  const float* ldsF = reinterpret_cast<const float*>(buf);
  const float4* cb4 = reinterpret_cast<const float4*>(cb);
  float* zqb = zq + (size_t)(bid >> 6) * 1048576 + (size_t)(bid & 63) * 64;
  for (int hp = 0; hp < 2; ++hp) {
    __syncthreads();
#pragma unroll
    for (int i = 0; i < 8; ++i) {
      int item = t + i * 256;            // rr = item>>6 in [0,32), cc = item&63
      int rr = item >> 6, cc = item & 63;
      float4 v = cb4[(size_t)bestj[hp * 32 + rr] * 64 + cc];
      ldsF4[rr * 64 + (cc ^ ((rr >> 2) & 7))] = (f32x4){v.x, v.y, v.z, v.w};
    }
    __syncthreads();
#pragma unroll
    for (int i = 0; i < 8; ++i) {
      int item = t + i * 256;            // w4p = item&7, c = item>>3
      int w4p = item & 7, c = item >> 3;
      float ov[4];
#pragma unroll
      for (int q = 0; q < 4; ++q) {
        int rr = w4p * 4 + q;
        ov[q] = ldsF[(rr * 64 + ((c >> 2) ^ ((rr >> 2) & 7))) * 4 + (c & 3)];
      }
      *reinterpret_cast<float4*>(zqb + (size_t)c * 4096 + hp * 32 + w4p * 4) =
          make_float4(ov[0], ov[1], ov[2], ov[3]);
    }
  }
}

// ---- exact rescore: batched 8 rows, coalesced zdump + cbT, idx-only ----
__global__ __launch_bounds__(256)
void vq_exact_fast(const float* __restrict__ zdump, const float* __restrict__ cbT,
                   const float* __restrict__ Bsg, const unsigned* __restrict__ list,
                   const unsigned* __restrict__ cnt, float* __restrict__ idxo) {
  __shared__ float zr[8][260];
  __shared__ float Anp[8];
  __shared__ float rv[256];
  __shared__ int ri[256];
  const int t = threadIdx.x;
  const unsigned K = *cnt;
  const float4* cbT4 = reinterpret_cast<const float4*>(cbT);
  const float4* zd4 = reinterpret_cast<const float4*>(zdump);

  for (unsigned g = blockIdx.x; g * 8 < K; g += gridDim.x) {
    int nrows = (int)min(8u, K - g * 8);
    __syncthreads();
#pragma unroll
    for (int i = 0; i < 2; ++i) {
      int idx = t + i * 256;             // r = idx>>6, c4 = idx&63
      int r = idx >> 6, c4 = idx & 63;
      if (r < nrows) {
        float4 v = zd4[(size_t)list[g * 8 + r] * 64 + c4];
        zr[r][c4 * 4 + 0] = v.x; zr[r][c4 * 4 + 1] = v.y;
        zr[r][c4 * 4 + 2] = v.z; zr[r][c4 * 4 + 3] = v.w;
      }
    }
    __syncthreads();
    if (t < nrows) Anp[t] = np_sumsq256(&zr[t][0], 1);
    __syncthreads();

    float acc[8][4];
#pragma unroll
    for (int r = 0; r < 8; ++r)
#pragma unroll
      for (int q = 0; q < 4; ++q) acc[r][q] = 0.f;
    for (int c = 0; c < 256; ++c) {
      float4 bv = cbT4[c * 256 + t];
#pragma unroll
      for (int r = 0; r < 8; ++r) {
        float zc = zr[r][c];
        acc[r][0] = fmaf(zc, bv.x, acc[r][0]);
        acc[r][1] = fmaf(zc, bv.y, acc[r][1]);
        acc[r][2] = fmaf(zc, bv.z, acc[r][2]);
        acc[r][3] = fmaf(zc, bv.w, acc[r][3]);
      }
    }
    for (int r = 0; r < nrows; ++r) {
      float A = Anp[r];
      float bvv = 3.4e38f;
      int bii = 0;
#pragma unroll
      for (int q = 0; q < 4; ++q) {
        int j = t * 4 + q;
        float dd = __fsub_rn(__fadd_rn(A, Bsg[j]), __fmul_rn(2.0f, acc[r][q]));
        if (dd < bvv) { bvv = dd; bii = j; }
      }
      rv[t] = bvv; ri[t] = bii;
      __syncthreads();
      for (int s2 = 128; s2 > 0; s2 >>= 1) {
        if (t < s2) {
          float v2 = rv[t + s2]; int i2 = ri[t + s2];
          if (v2 < rv[t] || (v2 == rv[t] && i2 < ri[t])) { rv[t] = v2; ri[t] = i2; }
        }
        __syncthreads();
      }
      if (t == 0) idxo[list[g * 8 + r]] = (float)ri[0];
      __syncthreads();
    }
  }
}

// ---- fallback (round-2 validated all-exact kernel) ----
__global__ __launch_bounds__(256)
void vq_ref(const float* __restrict__ z, const float* __restrict__ cb,
            float* __restrict__ zq, float* __restrict__ loss,
            float* __restrict__ idxo) {
  __shared__ __align__(16) float zt[256 * 64];
  __shared__ __align__(16) float cbt[256 * 64];
  __shared__ float As[64];
  __shared__ float Bs[64];
  __shared__ int bestj[64];
  __shared__ float cand_v[16 * 64];
  __shared__ int cand_i[16 * 64];
  __shared__ double wred[4];
  const int t = threadIdx.x;
  const int wg = t & 15, jg = t >> 4;
  const int bid = blockIdx.x;
  const int b = bid >> 6, h = bid & 63;
  const int n0 = bid * 64;
  const float4* z4 = reinterpret_cast<const float4*>(z + (size_t)b * 256 * 4096 + (size_t)h * 64);
  float4* zt4 = reinterpret_cast<float4*>(zt);
#pragma unroll
  for (int i = 0; i < 16; ++i) {
    int idx4 = t + i * 256;
    zt4[idx4] = z4[(size_t)(idx4 >> 4) * 1024 + (idx4 & 15)];
  }
  __syncthreads();
  if (t < 64) As[t] = np_sumsq256(zt + t, 64);
  float bv[4]; int bi[4];
#pragma unroll
  for (int a = 0; a < 4; ++a) { bv[a] = 3.4e38f; bi[a] = 0; }
  for (int p = 0; p < 16; ++p) {
    __syncthreads();
    const float4* cb4 = reinterpret_cast<const float4*>(cb) + (size_t)p * 64 * 64;
#pragma unroll
    for (int i = 0; i < 16; ++i) {
      int idx4 = t + i * 256;
      int jj = idx4 >> 6, c4 = idx4 & 63;
      float4 v = cb4[idx4];
      cbt[(c4 * 4 + 0) * 64 + jj] = v.x;
      cbt[(c4 * 4 + 1) * 64 + jj] = v.y;
      cbt[(c4 * 4 + 2) * 64 + jj] = v.z;
      cbt[(c4 * 4 + 3) * 64 + jj] = v.w;
    }
    __syncthreads();
    if (t < 64) Bs[t] = np_sumsq256(cbt + t, 64);
    float acc[4][4];
#pragma unroll
    for (int a = 0; a < 4; ++a)
#pragma unroll
      for (int u = 0; u < 4; ++u) acc[a][u] = 0.0f;
    const float4* ztp = reinterpret_cast<const float4*>(zt) + wg;
    const float4* cbp = reinterpret_cast<const float4*>(cbt) + jg;
#pragma unroll 4
    for (int c = 0; c < 256; ++c) {
      float4 zv = ztp[c * 16];
      float4 cv = cbp[c * 16];
      float za[4] = {zv.x, zv.y, zv.z, zv.w};
      float ca[4] = {cv.x, cv.y, cv.z, cv.w};
#pragma unroll
      for (int a = 0; a < 4; ++a)
#pragma unroll
        for (int u = 0; u < 4; ++u) acc[a][u] = fmaf(za[a], ca[u], acc[a][u]);
    }
    __syncthreads();
#pragma unroll
    for (int u = 0; u < 4; ++u) {
      int j = p * 64 + jg * 4 + u;
      float Bju = Bs[jg * 4 + u];
#pragma unroll
      for (int a = 0; a < 4; ++a) {
        float AB = __fadd_rn(As[wg * 4 + a], Bju);
        float dd = __fsub_rn(AB, __fmul_rn(2.0f, acc[a][u]));
        if (dd < bv[a]) { bv[a] = dd; bi[a] = j; }
      }
    }
  }
  __syncthreads();
#pragma unroll
  for (int a = 0; a < 4; ++a) {
    int w = wg * 4 + a;
    cand_v[jg * 64 + w] = bv[a];
    cand_i[jg * 64 + w] = bi[a];
  }
  __syncthreads();
  if (t < 64) {
    float v0 = cand_v[t]; int i0 = cand_i[t];
    for (int g = 1; g < 16; ++g) {
      float v = cand_v[g * 64 + t]; int ii = cand_i[g * 64 + t];
      if (v < v0 || (v == v0 && ii < i0)) { v0 = v; i0 = ii; }
    }
    bestj[t] = i0;
    idxo[n0 + t] = (float)i0;
  }
  __syncthreads();
  double lsum = 0.0;
  float* zqbase = zq + (size_t)b * 256 * 4096 + (size_t)h * 64;
  for (int i = 0; i < 64; ++i) {
    int idx = t + i * 256;
    int c = idx >> 6, w = idx & 63;
    float zvv = zt[c * 64 + w];
    float cvv = cb[(size_t)bestj[w] * 256 + c];
    zqbase[(size_t)c * 4096 + w] = cvv;
    double d = (double)cvv - (double)zvv;
    lsum += d * d;
  }
#pragma unroll
  for (int off = 32; off > 0; off >>= 1) lsum += __shfl_down(lsum, off, 64);
  if ((t & 63) == 0) wred[t >> 6] = lsum;
  __syncthreads();
  if (t == 0) {
    double tot = wred[0] + wred[1] + wred[2] + wred[3];
    atomicAdd(loss, (float)(tot * (1.25 / (double)NELEM)));
  }
}

extern "C" void kernel_launch(void* const* d_in, const int* in_sizes, int n_in,
                              void* d_out, int out_size, void* d_ws, size_t ws_size,
                              hipStream_t stream) {
  (void)in_sizes; (void)n_in; (void)out_size;
  const float* z = (const float*)d_in[0];
  const float* cb = (const float*)d_in[1];
  float* out = (float*)d_out;
  float* zq = out;
  float* loss = out + NELEM;
  float* idxo = out + NELEM + 1;
  if (ws_size < 35651584) {  // need zdump: else validated all-exact path
    hipMemsetAsync(loss, 0, sizeof(float), stream);
    vq_ref<<<512, 256, 0, stream>>>(z, cb, zq, loss, idxo);
    return;
  }
  unsigned char* ws = (unsigned char*)d_ws;
  unsigned* cnt = (unsigned*)ws;                             // 4 B
  float* Bsg = (float*)(ws + 1024);                          // 4 KB
  unsigned* list = (unsigned*)(ws + 8192);                   // 128 KB
  float* cbT = (float*)(ws + 139264);                        // 1 MB
  unsigned short* cbimg = (unsigned short*)(ws + 1187840);   // 512 KB fp16 frag-layout
  float* zdump = (float*)(ws + 2097152);                     // 32 MB
  vq_prep<<<64, 256, 0, stream>>>(cb, cbimg, cbT, Bsg, cnt, loss);
  vq_fast<<<512, 256, 0, stream>>>(z, cb, cbimg, Bsg, zq, loss, idxo, list, cnt, zdump);
  vq_exact_fast<<<512, 256, 0, stream>>>(zdump, cbT, Bsg, list, cnt, idxo);
}